// Round 2
// baseline (236.584 us; speedup 1.0000x reference)
//
#include <hip/hip_runtime.h>
#include <math.h>

#define TN 8192
#define AN 128

// ---- workspace layout (doubles) ----
#define WS_SUMSTD_B 0      // 64 banked accumulators
#define WS_CONC_B   64     // 64
#define WS_SUM10_B  128    // 64
#define WS_STD0     192
#define WS_STDL     193
#define WS_CNT20    194
#define WS_SUM10L5  195
#define WS_LAMBDA   196
#define WS_CSUM     197
#define WS_CTRACE   198
#define WS_CABS     199
#define WS_SEV      200
#define WS_CSB      256            // colsum banked [64][128]
#define WS_COV      8448           // 16384 doubles
#define WS_NZ_FAST  8448           // zero range (fast path)
#define WS_NZ_FB    24832          // zero range (fallback: includes COV)
// corr (float[16384]) at wsd+24832; gram partials after that (fast path)
#define SLICES      128
#define ROWS_PER_SLICE (TN / SLICES)   // 64
#define PART_BYTE_OFF  (24832 * 8 + 16384 * 4)        // 264192
#define WS_NEED_FAST   (PART_BYTE_OFF + SLICES * AN * AN * 4)  // 8652800

__global__ void k_zero(double* wsd, int n) {
  int i = blockIdx.x * 256 + threadIdx.x;
  if (i < n) wsd[i] = 0.0;
}

// ---------------- Gram, fast path: 8x8 register tiles ----------------
__global__ void __launch_bounds__(256) k_gram2(const float* __restrict__ x,
                                               float* __restrict__ part) {
  __shared__ float lds[8][AN];
  int tid = threadIdx.x;
  int i0 = (tid >> 4) * 8;
  int j0 = (tid & 15) * 8;
  int lrow = tid >> 5;           // 0..7
  int lcol = (tid & 31) * 4;     // 0..124
  const float* xs = x + (size_t)blockIdx.x * ROWS_PER_SLICE * AN;
  float acc[8][8];
#pragma unroll
  for (int a = 0; a < 8; ++a)
#pragma unroll
    for (int b = 0; b < 8; ++b) acc[a][b] = 0.f;
  float4 v = *(const float4*)(xs + lrow * AN + lcol);
  for (int it = 0; it < ROWS_PER_SLICE / 8; ++it) {
    __syncthreads();
    *(float4*)(&lds[lrow][lcol]) = v;
    __syncthreads();
    if (it + 1 < ROWS_PER_SLICE / 8)
      v = *(const float4*)(xs + ((it + 1) * 8 + lrow) * AN + lcol);
#pragma unroll
    for (int r = 0; r < 8; ++r) {
      float a[8], b[8];
      *(float4*)(a) = *(const float4*)(&lds[r][i0]);
      *(float4*)(a + 4) = *(const float4*)(&lds[r][i0 + 4]);
      *(float4*)(b) = *(const float4*)(&lds[r][j0]);
      *(float4*)(b + 4) = *(const float4*)(&lds[r][j0 + 4]);
#pragma unroll
      for (int ai = 0; ai < 8; ++ai)
#pragma unroll
        for (int bj = 0; bj < 8; ++bj)
          acc[ai][bj] = fmaf(a[ai], b[bj], acc[ai][bj]);
    }
  }
  float* dst = part + (size_t)blockIdx.x * (AN * AN);
#pragma unroll
  for (int ai = 0; ai < 8; ++ai)
#pragma unroll
    for (int bj = 0; bj < 8; bj += 4)
      *(float4*)(dst + (i0 + ai) * AN + j0 + bj) =
          make_float4(acc[ai][bj], acc[ai][bj + 1], acc[ai][bj + 2], acc[ai][bj + 3]);
}

// fold 128 fp32 partial grams -> fp64 cov
__global__ void __launch_bounds__(256) k_reduce(const float* __restrict__ part,
                                                double* __restrict__ wsd) {
  int e = blockIdx.x * 256 + threadIdx.x;  // 0..16383
  double s = 0.0;
  for (int b = 0; b < SLICES; ++b) s += (double)part[(size_t)b * AN * AN + e];
  wsd[WS_COV + e] = s;
}

// ---------------- Gram, fallback path (atomics, known-correct) --------
__global__ void __launch_bounds__(256) k_gram_fb(const float* __restrict__ x,
                                                 double* __restrict__ wsd) {
  int tid = threadIdx.x;
  int i = blockIdx.y * 16 + (tid >> 4);
  int j4 = (blockIdx.x * 16 + (tid & 15)) * 4;
  const float* p = x + (size_t)blockIdx.z * (TN / 16) * AN;
  float g0 = 0.f, g1 = 0.f, g2 = 0.f, g3 = 0.f;
#pragma unroll 4
  for (int t = 0; t < TN / 16; ++t, p += AN) {
    float xi = p[i];
    float4 xj = *(const float4*)(p + j4);
    g0 = fmaf(xi, xj.x, g0);
    g1 = fmaf(xi, xj.y, g1);
    g2 = fmaf(xi, xj.z, g2);
    g3 = fmaf(xi, xj.w, g3);
  }
  double* cov = wsd + WS_COV + i * AN + j4;
  atomicAdd(cov + 0, (double)g0);
  atomicAdd(cov + 1, (double)g1);
  atomicAdd(cov + 2, (double)g2);
  atomicAdd(cov + 3, (double)g3);
}

// -------- per-row stats (std, sign counts) + column sums, one pass ----
__global__ void __launch_bounds__(256) k_rowcol(const float* __restrict__ x,
                                                double* __restrict__ wsd) {
  __shared__ float csum[AN];
  int tid = threadIdx.x;
  int lane = tid & 63;
  int t = blockIdx.x * 4 + (tid >> 6);
  if (tid < AN) csum[tid] = 0.f;
  __syncthreads();
  const float* row = x + (size_t)t * AN;
  float x0 = row[lane], x1 = row[lane + 64];
  atomicAdd(&csum[lane], x0);
  atomicAdd(&csum[lane + 64], x1);
  float s = x0 + x1;
#pragma unroll
  for (int o = 32; o; o >>= 1) s += __shfl_xor(s, o);
  float mean = s * (1.0f / AN);
  float d0 = x0 - mean, d1 = x1 - mean;
  float q = d0 * d0 + d1 * d1;
#pragma unroll
  for (int o = 32; o; o >>= 1) q += __shfl_xor(q, o);
  float sd = sqrtf(q / (float)(AN - 1));
  int pk = (int)(x0 < 0.f) + (int)(x1 < 0.f)
         + (((int)(x0 == 0.f) + (int)(x1 == 0.f)) << 10)
         + (((int)(x0 > 0.f) + (int)(x1 > 0.f)) << 20);
#pragma unroll
  for (int o = 32; o; o >>= 1) pk += __shfl_xor(pk, o);
  if (lane == 0) {
    int nn = pk & 1023, nz = (pk >> 10) & 1023, np = (pk >> 20) & 1023;
    int b = blockIdx.x & 63;
    atomicAdd(&wsd[WS_CONC_B + b],
              (double)nn * nn + (double)nz * nz + (double)np * np);
    atomicAdd(&wsd[WS_SUMSTD_B + b], (double)sd);
    if (t == 0) wsd[WS_STD0] = (double)sd;
    if (t == TN - 1) wsd[WS_STDL] = (double)sd;
  }
  __syncthreads();
  if (tid < AN)
    atomicAdd(&wsd[WS_CSB + (blockIdx.x & 63) * AN + tid], (double)csum[tid]);
}

// ---------------- rolling off-diagonal correlation --------------------
// r = sum_t s_t^2, s_t = sum_lanes p_t. Butterfly with lane-compression:
// after summing over xor-bit o, pack two t's per lane selected by that bit.
// DS ops: W=20: 20+10+5+3+2+1+6=47 (vs 126); W=10: 10+5+3+2+1+1+6=28 (vs 66).
template <int W>
__global__ void __launch_bounds__(256) k_roll(const float* __restrict__ x,
                                              double* __restrict__ wsd, int nwin) {
  int lane = threadIdx.x & 63;
  int s = blockIdx.x * 4 + (threadIdx.x >> 6);
  if (s >= nwin) return;
  const float* base = x + (size_t)s * AN + lane;
  float x0[W], x1[W];
#pragma unroll
  for (int t = 0; t < W; ++t) {
    x0[t] = base[t * AN];
    x1[t] = base[t * AN + 64];
  }
  float s0 = 0.f, s1 = 0.f;
#pragma unroll
  for (int t = 0; t < W; ++t) { s0 += x0[t]; s1 += x1[t]; }
  float mu0 = s0 / W, mu1 = s1 / W;
  float v0 = 0.f, v1 = 0.f;
#pragma unroll
  for (int t = 0; t < W; ++t) {
    float a = x0[t] - mu0, b = x1[t] - mu1;
    v0 += a * a;
    v1 += b * b;
  }
  float a0 = 1.0f / sqrtf(v0), a1 = 1.0f / sqrtf(v1);
  float q[W];
#pragma unroll
  for (int t = 0; t < W; ++t)
    q[t] = (x0[t] - mu0) * a0 + (x1[t] - mu1) * a1;
  int n = W;
#pragma unroll
  for (int o = 1; o <= 32; o <<= 1) {
#pragma unroll
    for (int k = 0; k < n; ++k) q[k] += __shfl_xor(q[k], o);
    if (n > 1) {
      int nh = n >> 1;
      bool hi = (lane & o) != 0;
#pragma unroll
      for (int k = 0; k < nh; ++k) q[k] = hi ? q[2 * k + 1] : q[2 * k];
      if (n & 1) { q[nh] = q[2 * nh]; n = nh + 1; } else { n = nh; }
    }
  }
  // final per-lane weight = 1/multiplicity (traced: W=20 -> bit4: 2 vs 8;
  // W=10 -> bit3: 4 vs 16 lanes per t)
  float alpha = (W == 20) ? ((lane & 16) ? 0.125f : 0.5f)
                          : ((lane & 8) ? 0.0625f : 0.25f);
  float r = q[0] * q[0] * alpha;
#pragma unroll
  for (int o = 32; o; o >>= 1) r += __shfl_xor(r, o);
  if (lane == 0) {
    double off = ((double)r - (double)AN) / ((double)AN * (AN - 1));
    if (W == 20) {
      if (off > 0.7) atomicAdd(&wsd[WS_CNT20], 1.0);
    } else {
      atomicAdd(&wsd[WS_SUM10_B + (s & 63)], off);
      if (s >= TN - W - 5) atomicAdd(&wsd[WS_SUM10L5], off);
    }
  }
}

// ---- corr finalize (normalize cov, reductions) + power iteration -----
__global__ void __launch_bounds__(256) k_spec(double* __restrict__ wsd,
                                              float* __restrict__ corr) {
  __shared__ double dsh[AN];
  __shared__ double msh[AN];
  __shared__ double r0[256], r1[256], r2[256];
  int p = threadIdx.x;
  if (p < AN) {
    double cs = 0.0;
    for (int b = 0; b < 64; ++b) cs += wsd[WS_CSB + b * AN + p];
    double mu = cs / (double)TN;
    msh[p] = mu;
    double cv = wsd[WS_COV + p * AN + p] - (double)TN * mu * mu;
    dsh[p] = sqrt(cv);
  }
  __syncthreads();
  double sa = 0.0, sb = 0.0, st = 0.0;
  for (int idx = p; idx < AN * AN; idx += 256) {
    int i = idx >> 7, j = idx & (AN - 1);
    double cv = wsd[WS_COV + idx] - (double)TN * msh[i] * msh[j];
    double c = cv / (dsh[i] * dsh[j]);
    corr[idx] = (float)c;
    sa += c;
    sb += fabs(c);
    if (i == j) st += c;
  }
  r0[p] = sa; r1[p] = sb; r2[p] = st;
  __syncthreads();
  for (int sft = 128; sft; sft >>= 1) {
    if (p < sft) { r0[p] += r0[p + sft]; r1[p] += r1[p + sft]; r2[p] += r2[p + sft]; }
    __syncthreads();
  }
  if (p == 0) {
    wsd[WS_CSUM] = r0[0];
    wsd[WS_CABS] = r1[0];
    wsd[WS_CTRACE] = r2[0];
  }
  __syncthreads();
  // ---- power iteration (corr just written by this block; visible after sync)
  __shared__ float v[AN];
  __shared__ float part[256];
  __shared__ float un[AN];
  __shared__ float red[AN];
  int i = p & (AN - 1);
  int h = p >> 7;
  float4 row[16];
  const float4* src = (const float4*)(corr + i * AN + h * 64);
#pragma unroll
  for (int k = 0; k < 16; ++k) row[k] = src[k];
  if (p < AN) v[p] = 1.0f;
  __syncthreads();
  float lam = 0.0f;
  for (int it = 0; it < 12; ++it) {
    const float4* vp = (const float4*)(v + h * 64);
    float acc = 0.f;
#pragma unroll
    for (int k = 0; k < 16; ++k) {
      float4 a = row[k], b = vp[k];
      acc += a.x * b.x + a.y * b.y + a.z * b.z + a.w * b.w;
    }
    part[p] = acc;
    __syncthreads();
    if (p < AN) {
      float u = part[p] + part[p + 128];
      un[p] = u;
      red[p] = u * u;
    }
    __syncthreads();
    for (int sft = 64; sft; sft >>= 1) {
      if (p < sft) red[p] += red[p + sft];
      __syncthreads();
    }
    lam = sqrtf(red[0]);
    if (p < AN) v[p] = un[p] / lam;
    __syncthreads();
  }
  if (p == 0) wsd[WS_LAMBDA] = (double)lam;
}

// -------- MLP (BatchNorm eval) + final assembly of the 8 outputs ------
__global__ void __launch_bounds__(256) k_tail(
    const float* __restrict__ x, const float* __restrict__ pos,
    const float* __restrict__ w1, const float* __restrict__ b1,
    const float* __restrict__ gamma, const float* __restrict__ beta,
    const float* __restrict__ w2, const float* __restrict__ b2,
    const float* __restrict__ w3, const float* __restrict__ b3,
    double* __restrict__ wsd, float* __restrict__ out) {
  __shared__ float f[2 * AN];
  __shared__ float h1[AN];
  __shared__ float h2[64];
  __shared__ float lg[3];
  int t = threadIdx.x;
  f[t] = (t < AN) ? x[(size_t)(TN - 1) * AN + t] : pos[t - AN];
  __syncthreads();
  if (t < AN) {
    float acc = b1[t];
    for (int k = 0; k < 2 * AN; ++k) acc = fmaf(f[k], w1[k * AN + t], acc);
    acc = fmaxf(acc, 0.0f);
    acc = gamma[t] * (acc / sqrtf(1.0f + 1e-5f)) + beta[t];
    h1[t] = acc;
  }
  __syncthreads();
  if (t < 64) {
    float acc = b2[t];
    for (int k = 0; k < AN; ++k) acc = fmaf(h1[k], w2[k * 64 + t], acc);
    h2[t] = fmaxf(acc, 0.0f);
  }
  __syncthreads();
  if (t < 3) {
    float acc = b3[t];
    for (int k = 0; k < 64; ++k) acc = fmaf(h2[k], w3[k * 3 + t], acc);
    lg[t] = acc;
  }
  __syncthreads();
  if (t != 0) return;
  float m = fmaxf(lg[0], fmaxf(lg[1], lg[2]));
  float e0 = expf(lg[0] - m), e1 = expf(lg[1] - m), e2 = expf(lg[2] - m);
  double sev = (double)(e2 / (e0 + e1 + e2));
  double sumstd = 0.0, conc = 0.0, sum10 = 0.0;
  for (int k = 0; k < 64; ++k) {
    sumstd += wsd[WS_SUMSTD_B + k];
    conc += wsd[WS_CONC_B + k];
    sum10 += wsd[WS_SUM10_B + k];
  }
  double avg_disp = sumstd / (double)TN;
  double trend = -(wsd[WS_STDL] - wsd[WS_STD0]) / (double)(TN - 1);
  double hi = trend / (avg_disp + 1e-6) + 0.5;
  hi = fmin(1.0, fmax(0.0, hi));
  double avg_corr = (wsd[WS_CSUM] - wsd[WS_CTRACE]) / ((double)AN * (AN - 1));
  double sync_ind = wsd[WS_LAMBDA] / (double)AN;
  double sync_risk = fmin(1.0, sync_ind * avg_corr);
  double pl = wsd[WS_CNT20] / (double)(TN - 20);
  double rd = 1.0 - wsd[WS_CABS] / ((double)AN * AN);
  double pasum = 0.0, pamax = 0.0;
  for (int k = 0; k < AN; ++k) {
    double pa = fabs((double)pos[k]);
    pasum += pa;
    if (pa > pamax) pamax = pa;
  }
  double pd = 1.0 - pamax / pasum;
  double dl = 1.0 - sqrt(rd * pd);
  double recent = wsd[WS_SUM10L5] / 5.0;
  double hist = (sum10 - wsd[WS_SUM10L5]) / (double)(TN - 10 - 5);
  double sraw = (recent - hist) / hist;
  sraw = fmin(1.0, fmax(0.0, sraw));
  double surge = (hist > 0.0) ? sraw : 0.0;
  double ac = (conc / (double)TN - (double)AN) / ((double)AN * (AN - 1));
  double pc = fmin(1.0, fmax(0.0, (ac - 0.5) * 2.0));
  double cr = (hi + sync_risk + dl) / 3.0;
  out[0] = (float)hi;
  out[1] = (float)sev;
  out[2] = (float)sync_risk;
  out[3] = (float)pl;
  out[4] = (float)dl;
  out[5] = (float)surge;
  out[6] = (float)pc;
  out[7] = (float)cr;
}

extern "C" void kernel_launch(void* const* d_in, const int* in_sizes, int n_in,
                              void* d_out, int out_size, void* d_ws, size_t ws_size,
                              hipStream_t stream) {
  const float* x     = (const float*)d_in[0];
  const float* pos   = (const float*)d_in[1];
  const float* w1    = (const float*)d_in[2];
  const float* b1    = (const float*)d_in[3];
  const float* gamma = (const float*)d_in[4];
  const float* beta  = (const float*)d_in[5];
  const float* w2    = (const float*)d_in[6];
  const float* b2    = (const float*)d_in[7];
  const float* w3    = (const float*)d_in[8];
  const float* b3    = (const float*)d_in[9];
  float* out = (float*)d_out;
  double* wsd = (double*)d_ws;
  float* corr = (float*)(wsd + 24832);
  float* part = (float*)((char*)d_ws + PART_BYTE_OFF);
  bool fast = ws_size >= (size_t)WS_NEED_FAST;

  if (fast) {
    k_zero<<<(WS_NZ_FAST + 255) / 256, 256, 0, stream>>>(wsd, WS_NZ_FAST);
    k_gram2<<<SLICES, 256, 0, stream>>>(x, part);
    k_reduce<<<64, 256, 0, stream>>>(part, wsd);
  } else {
    k_zero<<<(WS_NZ_FB + 255) / 256, 256, 0, stream>>>(wsd, WS_NZ_FB);
    k_gram_fb<<<dim3(2, 8, 16), 256, 0, stream>>>(x, wsd);
  }
  k_rowcol<<<TN / 4, 256, 0, stream>>>(x, wsd);
  k_roll<20><<<(TN - 20 + 3) / 4, 256, 0, stream>>>(x, wsd, TN - 20);
  k_roll<10><<<(TN - 10 + 3) / 4, 256, 0, stream>>>(x, wsd, TN - 10);
  k_spec<<<1, 256, 0, stream>>>(wsd, corr);
  k_tail<<<1, 256, 0, stream>>>(x, pos, w1, b1, gamma, beta, w2, b2, w3, b3,
                                wsd, out);
}

// Round 3
// 137.996 us; speedup vs baseline: 1.7144x; 1.7144x over previous
//
#include <hip/hip_runtime.h>
#include <math.h>

#define TN 8192
#define AN 128

// ---- grid ranges for k_main ----
#define B_GRAM 128
#define B_ROW  512
#define NW20   (TN - 20)            // 8172
#define NW10   (TN - 10)            // 8182
#define B_R20  2043                 // ceil(8172/4)
#define B_R10  2046                 // ceil(8182/4)
#define B_TOTAL (B_GRAM + B_ROW + B_R20 + B_R10)   // 4729

// ---- workspace layout (double indices) ----
#define WS_STD0    0
#define WS_STDL    1
#define WS_SUMSTD  2
#define WS_CONC    3
#define WS_SUM10   4
#define WS_SUM10L5 5
#define WS_CNT20   6
#define WS_SPEC    64        // [64][3] per-block {sum, sumabs, trace}
#define WS_ROWP    256       // [512][2] per-block {sumstd, conc}
#define WS_R20V    1280      // [8172] per-window offdiag
#define WS_R10V    9452      // [8182]
#define WS_DEND    17664     // doubles end (padded)
// floats after: corr[16384], colsum parts[128*128], diag parts[128*128],
//               gram parts[128*16384]

// rolling off-diag corr via C.sum() = sum_t (sum_i z_ti)^2, butterfly with
// lane-compression (verified r1/r2: absmax 7e-9)
template <int W>
__device__ __forceinline__ double roll_off(const float* __restrict__ base,
                                           int lane) {
  float x0[W], x1[W];
#pragma unroll
  for (int t = 0; t < W; ++t) {
    x0[t] = base[t * AN + lane];
    x1[t] = base[t * AN + lane + 64];
  }
  float s0 = 0.f, s1 = 0.f;
#pragma unroll
  for (int t = 0; t < W; ++t) { s0 += x0[t]; s1 += x1[t]; }
  float mu0 = s0 / W, mu1 = s1 / W;
  float v0 = 0.f, v1 = 0.f;
#pragma unroll
  for (int t = 0; t < W; ++t) {
    float a = x0[t] - mu0, b = x1[t] - mu1;
    v0 += a * a;
    v1 += b * b;
  }
  float a0 = 1.0f / sqrtf(v0), a1 = 1.0f / sqrtf(v1);
  float q[W];
#pragma unroll
  for (int t = 0; t < W; ++t)
    q[t] = (x0[t] - mu0) * a0 + (x1[t] - mu1) * a1;
  int n = W;
#pragma unroll
  for (int o = 1; o <= 32; o <<= 1) {
#pragma unroll
    for (int k = 0; k < n; ++k) q[k] += __shfl_xor(q[k], o);
    if (n > 1) {
      int nh = n >> 1;
      bool hi = (lane & o) != 0;
#pragma unroll
      for (int k = 0; k < nh; ++k) q[k] = hi ? q[2 * k + 1] : q[2 * k];
      if (n & 1) { q[nh] = q[2 * nh]; n = nh + 1; } else { n = nh; }
    }
  }
  float alpha = (W == 20) ? ((lane & 16) ? 0.125f : 0.5f)
                          : ((lane & 8) ? 0.0625f : 0.25f);
  float r = q[0] * q[0] * alpha;
#pragma unroll
  for (int o = 32; o; o >>= 1) r += __shfl_xor(r, o);
  return ((double)r - (double)AN) / ((double)AN * (AN - 1));
}

// ---------------- phase A: everything data-parallel, one kernel -------
__global__ void __launch_bounds__(256) k_main(const float* __restrict__ x,
                                              double* __restrict__ wsd,
                                              float* __restrict__ pc,
                                              float* __restrict__ pdg,
                                              float* __restrict__ pg) {
  int bx = blockIdx.x;
  int tid = threadIdx.x;
  if (bx < B_GRAM) {
    // ---- gram slice: 64 rows, 8x8 register tiles ----
    __shared__ float lds[8][AN];
    int i0 = (tid >> 4) * 8;
    int j0 = (tid & 15) * 8;
    int lrow = tid >> 5;
    int lcol = (tid & 31) * 4;
    const float* xs = x + (size_t)bx * 64 * AN;
    float acc[8][8];
#pragma unroll
    for (int a = 0; a < 8; ++a)
#pragma unroll
      for (int b = 0; b < 8; ++b) acc[a][b] = 0.f;
    float4 v = *(const float4*)(xs + lrow * AN + lcol);
    for (int it = 0; it < 8; ++it) {
      __syncthreads();
      *(float4*)(&lds[lrow][lcol]) = v;
      __syncthreads();
      if (it + 1 < 8)
        v = *(const float4*)(xs + ((it + 1) * 8 + lrow) * AN + lcol);
#pragma unroll
      for (int r = 0; r < 8; ++r) {
        float a[8], b[8];
        *(float4*)(a) = *(const float4*)(&lds[r][i0]);
        *(float4*)(a + 4) = *(const float4*)(&lds[r][i0 + 4]);
        *(float4*)(b) = *(const float4*)(&lds[r][j0]);
        *(float4*)(b + 4) = *(const float4*)(&lds[r][j0 + 4]);
#pragma unroll
        for (int ai = 0; ai < 8; ++ai)
#pragma unroll
          for (int bj = 0; bj < 8; ++bj)
            acc[ai][bj] = fmaf(a[ai], b[bj], acc[ai][bj]);
      }
    }
    float* dst = pg + (size_t)bx * (AN * AN);
#pragma unroll
    for (int ai = 0; ai < 8; ++ai)
#pragma unroll
      for (int bj = 0; bj < 8; bj += 4)
        *(float4*)(dst + (i0 + ai) * AN + j0 + bj) =
            make_float4(acc[ai][bj], acc[ai][bj + 1], acc[ai][bj + 2],
                        acc[ai][bj + 3]);
    if ((tid >> 4) == (tid & 15)) {   // diagonal owner threads
#pragma unroll
      for (int k = 0; k < 8; ++k) pdg[bx * AN + i0 + k] = acc[k][k];
    }
    if (tid < AN) {                   // per-slice column sums
      float cs = 0.f;
      for (int r = 0; r < 64; ++r) cs += xs[r * AN + tid];
      pc[bx * AN + tid] = cs;
    }
  } else if (bx < B_GRAM + B_ROW) {
    // ---- per-row std + sign-concordance counts, 16 rows/block ----
    __shared__ double acc2[4][2];
    int rb = bx - B_GRAM;
    int lane = tid & 63;
    int w = tid >> 6;
    double sstd = 0.0, sconc = 0.0;
    for (int rr = 0; rr < 4; ++rr) {
      int t = rb * 16 + w * 4 + rr;
      const float* row = x + (size_t)t * AN;
      float x0 = row[lane], x1 = row[lane + 64];
      float s = x0 + x1;
#pragma unroll
      for (int o = 32; o; o >>= 1) s += __shfl_xor(s, o);
      float mean = s * (1.0f / AN);
      float d0 = x0 - mean, d1 = x1 - mean;
      float q = d0 * d0 + d1 * d1;
#pragma unroll
      for (int o = 32; o; o >>= 1) q += __shfl_xor(q, o);
      float sd = sqrtf(q / (float)(AN - 1));
      int pk = (int)(x0 < 0.f) + (int)(x1 < 0.f)
             + (((int)(x0 == 0.f) + (int)(x1 == 0.f)) << 10)
             + (((int)(x0 > 0.f) + (int)(x1 > 0.f)) << 20);
#pragma unroll
      for (int o = 32; o; o >>= 1) pk += __shfl_xor(pk, o);
      if (lane == 0) {
        int nn = pk & 1023, nz = (pk >> 10) & 1023, np = (pk >> 20) & 1023;
        sconc += (double)nn * nn + (double)nz * nz + (double)np * np;
        sstd += (double)sd;
        if (t == 0) wsd[WS_STD0] = (double)sd;
        if (t == TN - 1) wsd[WS_STDL] = (double)sd;
      }
    }
    if (lane == 0) { acc2[w][0] = sstd; acc2[w][1] = sconc; }
    __syncthreads();
    if (tid == 0) {
      wsd[WS_ROWP + rb * 2 + 0] = acc2[0][0] + acc2[1][0] + acc2[2][0] + acc2[3][0];
      wsd[WS_ROWP + rb * 2 + 1] = acc2[0][1] + acc2[1][1] + acc2[2][1] + acc2[3][1];
    }
  } else if (bx < B_GRAM + B_ROW + B_R20) {
    int s = (bx - (B_GRAM + B_ROW)) * 4 + (tid >> 6);
    int lane = tid & 63;
    if (s < NW20) {
      double off = roll_off<20>(x + (size_t)s * AN, lane);
      if (lane == 0) wsd[WS_R20V + s] = off;
    }
  } else {
    int s = (bx - (B_GRAM + B_ROW + B_R20)) * 4 + (tid >> 6);
    int lane = tid & 63;
    if (s < NW10) {
      double off = roll_off<10>(x + (size_t)s * AN, lane);
      if (lane == 0) wsd[WS_R10V + s] = off;
    }
  }
}

// ------- phase B: fold partials -> cov -> corr + scalar folds ---------
__global__ void __launch_bounds__(256) k_fold(const float* __restrict__ pc,
                                              const float* __restrict__ pdg,
                                              const float* __restrict__ pg,
                                              double* __restrict__ wsd,
                                              float* __restrict__ corr) {
  __shared__ double r0[256], r1[256], r2[256], r3[256], r4[256];
  int b = blockIdx.x;
  int t = threadIdx.x;
  if (b < 64) {
    __shared__ double muS[AN], dS[AN];
    if (t < AN) {
      double cs = 0.0, dg = 0.0;
      for (int s = 0; s < B_GRAM; ++s) {
        cs += (double)pc[s * AN + t];
        dg += (double)pdg[s * AN + t];
      }
      double mu = cs / (double)TN;
      muS[t] = mu;
      dS[t] = sqrt(dg - (double)TN * mu * mu);
    }
    __syncthreads();
    int e = b * 256 + t;
    int i = e >> 7, j = e & (AN - 1);
    double cv = 0.0;
    for (int s = 0; s < B_GRAM; ++s) cv += (double)pg[(size_t)s * (AN * AN) + e];
    cv -= (double)TN * muS[i] * muS[j];
    double c = cv / (dS[i] * dS[j]);
    corr[e] = (float)c;
    r0[t] = c;
    r1[t] = fabs(c);
    r2[t] = (i == j) ? c : 0.0;
    __syncthreads();
    for (int sft = 128; sft; sft >>= 1) {
      if (t < sft) { r0[t] += r0[t + sft]; r1[t] += r1[t + sft]; r2[t] += r2[t + sft]; }
      __syncthreads();
    }
    if (t == 0) {
      wsd[WS_SPEC + b * 3 + 0] = r0[0];
      wsd[WS_SPEC + b * 3 + 1] = r1[0];
      wsd[WS_SPEC + b * 3 + 2] = r2[0];
    }
  } else {
    double a = 0.0, bc = 0.0, cnt = 0.0, s10 = 0.0, s10l5 = 0.0;
    for (int k = t; k < 512; k += 256) {
      a += wsd[WS_ROWP + 2 * k];
      bc += wsd[WS_ROWP + 2 * k + 1];
    }
    for (int k = t; k < NW20; k += 256)
      cnt += (wsd[WS_R20V + k] > 0.7) ? 1.0 : 0.0;
    for (int k = t; k < NW10; k += 256) {
      double v = wsd[WS_R10V + k];
      s10 += v;
      if (k >= NW10 - 5) s10l5 += v;
    }
    r0[t] = a; r1[t] = bc; r2[t] = cnt; r3[t] = s10; r4[t] = s10l5;
    __syncthreads();
    for (int sft = 128; sft; sft >>= 1) {
      if (t < sft) {
        r0[t] += r0[t + sft]; r1[t] += r1[t + sft]; r2[t] += r2[t + sft];
        r3[t] += r3[t + sft]; r4[t] += r4[t + sft];
      }
      __syncthreads();
    }
    if (t == 0) {
      wsd[WS_SUMSTD] = r0[0];
      wsd[WS_CONC] = r1[0];
      wsd[WS_CNT20] = r2[0];
      wsd[WS_SUM10] = r3[0];
      wsd[WS_SUM10L5] = r4[0];
    }
  }
}

// ------- phase C: power iteration (corr in LDS) + MLP + assembly ------
__global__ void __launch_bounds__(256) k_spec_tail(
    const float* __restrict__ x, const float* __restrict__ pos,
    const float* __restrict__ w1, const float* __restrict__ b1,
    const float* __restrict__ gamma, const float* __restrict__ beta,
    const float* __restrict__ w2, const float* __restrict__ b2,
    const float* __restrict__ w3, const float* __restrict__ b3,
    const double* __restrict__ wsd, const float* __restrict__ corr,
    float* __restrict__ out) {
  __shared__ float cS[128 * 130];       // padded rows: 4-way max bank aliasing
  __shared__ float vv[AN], prt[256], un[AN], red[AN];
  __shared__ double spec[3];
  __shared__ float f[2 * AN], h1[AN], h2[64], lg[3];
  int t = threadIdx.x;
  for (int e = t; e < AN * AN; e += 256)
    cS[(e >> 7) * 130 + (e & (AN - 1))] = corr[e];
  if (t < 64) {                         // wave 0: fold spec partials
    double s0 = wsd[WS_SPEC + t * 3 + 0];
    double s1 = wsd[WS_SPEC + t * 3 + 1];
    double s2 = wsd[WS_SPEC + t * 3 + 2];
#pragma unroll
    for (int o = 32; o; o >>= 1) {
      s0 += __shfl_xor(s0, o);
      s1 += __shfl_xor(s1, o);
      s2 += __shfl_xor(s2, o);
    }
    if (t == 0) { spec[0] = s0; spec[1] = s1; spec[2] = s2; }
  }
  f[t] = (t < AN) ? x[(size_t)(TN - 1) * AN + t] : pos[t - AN];
  if (t < AN) vv[t] = 1.0f;
  __syncthreads();
  // ---- power iteration, 12 iters, all from LDS ----
  int i = t & (AN - 1);
  int h = t >> 7;
  float lam = 0.0f;
  for (int it = 0; it < 12; ++it) {
    float acc = 0.f;
    const float* rowp = &cS[i * 130 + h * 64];
    const float* vp = &vv[h * 64];
#pragma unroll
    for (int k = 0; k < 64; k += 2) {
      float2 a = *(const float2*)(rowp + k);
      acc += a.x * vp[k] + a.y * vp[k + 1];
    }
    prt[t] = acc;
    __syncthreads();
    if (t < AN) {
      float u = prt[t] + prt[t + 128];
      un[t] = u;
      red[t] = u * u;
    }
    __syncthreads();
    for (int sft = 64; sft; sft >>= 1) {
      if (t < sft) red[t] += red[t + sft];
      __syncthreads();
    }
    lam = sqrtf(red[0]);
    if (t < AN) vv[t] = un[t] / lam;
    __syncthreads();
  }
  // ---- MLP ----
  if (t < AN) {
    float acc = b1[t];
    for (int k = 0; k < 2 * AN; ++k) acc = fmaf(f[k], w1[k * AN + t], acc);
    acc = fmaxf(acc, 0.0f);
    acc = gamma[t] * (acc / sqrtf(1.0f + 1e-5f)) + beta[t];
    h1[t] = acc;
  }
  __syncthreads();
  if (t < 64) {
    float acc = b2[t];
    for (int k = 0; k < AN; ++k) acc = fmaf(h1[k], w2[k * 64 + t], acc);
    h2[t] = fmaxf(acc, 0.0f);
  }
  __syncthreads();
  if (t < 3) {
    float acc = b3[t];
    for (int k = 0; k < 64; ++k) acc = fmaf(h2[k], w3[k * 3 + t], acc);
    lg[t] = acc;
  }
  __syncthreads();
  if (t != 0) return;
  float m = fmaxf(lg[0], fmaxf(lg[1], lg[2]));
  float e0 = expf(lg[0] - m), e1 = expf(lg[1] - m), e2 = expf(lg[2] - m);
  double sev = (double)(e2 / (e0 + e1 + e2));
  double avg_disp = wsd[WS_SUMSTD] / (double)TN;
  double trend = -(wsd[WS_STDL] - wsd[WS_STD0]) / (double)(TN - 1);
  double hi = trend / (avg_disp + 1e-6) + 0.5;
  hi = fmin(1.0, fmax(0.0, hi));
  double avg_corr = (spec[0] - spec[2]) / ((double)AN * (AN - 1));
  double sync_ind = (double)lam / (double)AN;
  double sync_risk = fmin(1.0, sync_ind * avg_corr);
  double pl = wsd[WS_CNT20] / (double)(TN - 20);
  double rd = 1.0 - spec[1] / ((double)AN * AN);
  double pasum = 0.0, pamax = 0.0;
  for (int k = 0; k < AN; ++k) {
    double pa = fabs((double)pos[k]);
    pasum += pa;
    if (pa > pamax) pamax = pa;
  }
  double pd = 1.0 - pamax / pasum;
  double dl = 1.0 - sqrt(rd * pd);
  double recent = wsd[WS_SUM10L5] / 5.0;
  double hist = (wsd[WS_SUM10] - wsd[WS_SUM10L5]) / (double)(TN - 10 - 5);
  double sraw = (recent - hist) / hist;
  sraw = fmin(1.0, fmax(0.0, sraw));
  double surge = (hist > 0.0) ? sraw : 0.0;
  double ac = (wsd[WS_CONC] / (double)TN - (double)AN) / ((double)AN * (AN - 1));
  double pc = fmin(1.0, fmax(0.0, (ac - 0.5) * 2.0));
  double cr = (hi + sync_risk + dl) / 3.0;
  out[0] = (float)hi;
  out[1] = (float)sev;
  out[2] = (float)sync_risk;
  out[3] = (float)pl;
  out[4] = (float)dl;
  out[5] = (float)surge;
  out[6] = (float)pc;
  out[7] = (float)cr;
}

extern "C" void kernel_launch(void* const* d_in, const int* in_sizes, int n_in,
                              void* d_out, int out_size, void* d_ws, size_t ws_size,
                              hipStream_t stream) {
  const float* x     = (const float*)d_in[0];
  const float* pos   = (const float*)d_in[1];
  const float* w1    = (const float*)d_in[2];
  const float* b1    = (const float*)d_in[3];
  const float* gamma = (const float*)d_in[4];
  const float* beta  = (const float*)d_in[5];
  const float* w2    = (const float*)d_in[6];
  const float* b2    = (const float*)d_in[7];
  const float* w3    = (const float*)d_in[8];
  const float* b3    = (const float*)d_in[9];
  float* out = (float*)d_out;
  double* wsd = (double*)d_ws;
  float* corr = (float*)(wsd + WS_DEND);     // [16384]
  float* pc   = corr + AN * AN;              // colsum partials [128*128]
  float* pdg  = pc + B_GRAM * AN;            // diag partials   [128*128]
  float* pg   = pdg + B_GRAM * AN;           // gram partials   [128*16384]

  k_main<<<B_TOTAL, 256, 0, stream>>>(x, wsd, pc, pdg, pg);
  k_fold<<<65, 256, 0, stream>>>(pc, pdg, pg, wsd, corr);
  k_spec_tail<<<1, 256, 0, stream>>>(x, pos, w1, b1, gamma, beta, w2, b2,
                                     w3, b3, wsd, corr, out);
}